// Round 13
// baseline (341.969 us; speedup 1.0000x reference)
//
#include <hip/hip_runtime.h>
#include <cstdint>
#include <cstddef>

typedef unsigned short u16;
typedef unsigned int u32;

#define NN 50000
#define NE 800000

typedef __attribute__((ext_vector_type(8))) short bf16x8;
typedef __attribute__((ext_vector_type(4))) float f32x4;

__device__ __forceinline__ u16 f2bf(float f) {
  union { float f; u32 i; } v; v.f = f;
  return (u16)((v.i + 0x7FFFu + ((v.i >> 16) & 1u)) >> 16);
}
__device__ __forceinline__ void bf2x2(u32 w, float& a, float& b) {
  union { u32 i; float f; } lo, hi;
  lo.i = w << 16; hi.i = w & 0xFFFF0000u;
  a = lo.f; b = hi.f;
}
__device__ __forceinline__ void unpack8(const uint4& q, float* f) {
  bf2x2(q.x, f[0], f[1]); bf2x2(q.y, f[2], f[3]);
  bf2x2(q.z, f[4], f[5]); bf2x2(q.w, f[6], f[7]);
}

#define XGROUPS (NN * 256 / 4)   // 3.2M float4 groups of x
#define NA_B 782                 // ceil(NE/1024) atomic blocks (ILP-4)
// cast blocks needed: (XGROUPS+294912)/256 = 13652 exactly.
// T_B=14455: #atomic(b%18==17) = 803 (last is no-op), #cast = 13652. ci is a
// bijection onto [0,13652): b=18m+r (r<17) -> ci=17m+r; b=14454 -> ci=13651.
#define T_B 14455

// ---------- fused: histogram(+slot, ILP-4) interleaved 1:17 with casts ----------
__global__ void k_hist_cast(const int* __restrict__ dst,
                            int* __restrict__ cnt, int* __restrict__ slot,
                            const float* __restrict__ x, const float* __restrict__ W1,
                            const float* __restrict__ W2, const float* __restrict__ W3,
                            u16* __restrict__ xb, u16* __restrict__ Wt1,
                            u16* __restrict__ Wt2, u16* __restrict__ Wt3) {
  int b = blockIdx.x;
  int q = b / 18, r = b - q * 18;
  if (r == 17) {
    if (q >= NA_B) return;
    int ebase = q * 1024 + threadIdx.x;
    int ds[4]; bool ok[4];
#pragma unroll
    for (int u = 0; u < 4; u++) {
      int e = ebase + u * 256;
      ok[u] = e < NE;
      ds[u] = ok[u] ? dst[e] : 0;
    }
    int sl[4];
#pragma unroll
    for (int u = 0; u < 4; u++)
      if (ok[u]) sl[u] = atomicAdd(&cnt[ds[u]], 1);
#pragma unroll
    for (int u = 0; u < 4; u++)
      if (ok[u]) slot[ebase + u * 256] = sl[u];
  } else {
    int ci = b - q;  // cast-block index (atomic blocks before b = q)
    int i = ci * 256 + threadIdx.x;
    if (i < XGROUPS) {
      float4 f = ((const float4*)x)[i];
      uint2 u;
      u.x = (u32)f2bf(f.x) | ((u32)f2bf(f.y) << 16);
      u.y = (u32)f2bf(f.z) | ((u32)f2bf(f.w) << 16);
      ((uint2*)xb)[i] = u;
    } else {
      int j = i - XGROUPS;
      if (j < 131072) {                    // W1: [256][512] -> Wt1[512][256]
        int k = j >> 9, n = j & 511;
        Wt1[n * 256 + k] = f2bf(W1[j]);
      } else if (j < 262144) {             // W2: [512][256] -> Wt2[256][512]
        int j2 = j - 131072;
        int k = j2 >> 8, n = j2 & 255;
        Wt2[n * 512 + k] = f2bf(W2[j2]);
      } else if (j < 294912) {             // W3: [256][128] -> Wt3[128][256]
        int j2 = j - 262144;
        int k = j2 >> 7, n = j2 & 127;
        Wt3[n * 256 + k] = f2bf(W3[j2]);
      }
    }
  }
}

__global__ void k_scan_part(const int* __restrict__ cnt, int* __restrict__ bsum, int n) {
  __shared__ int s[256];
  int i = blockIdx.x * 256 + threadIdx.x;
  s[threadIdx.x] = (i < n) ? cnt[i] : 0;
  __syncthreads();
  for (int o = 128; o > 0; o >>= 1) {
    if (threadIdx.x < o) s[threadIdx.x] += s[threadIdx.x + o];
    __syncthreads();
  }
  if (threadIdx.x == 0) bsum[blockIdx.x] = s[0];
}
// scan_fin with the inter-block prefix computed in-block
__global__ void k_scan_fin(const int* __restrict__ cnt, const int* __restrict__ bsum,
                           int* __restrict__ rowptr, int n) {
  __shared__ int s[256];
  __shared__ int pre[256];
  int t = threadIdx.x;
  int i = blockIdx.x * 256 + t;
  pre[t] = (t < blockIdx.x) ? bsum[t] : 0;  // nb <= 256
  s[t] = (i < n) ? cnt[i] : 0;
  __syncthreads();
  for (int o = 128; o > 0; o >>= 1) {
    if (t < o) pre[t] += pre[t + o];
    __syncthreads();
  }
  if (t == 0) {
    int run = pre[0];
    for (int j = 0; j < 256; j++) { int v = s[j]; s[j] = run; run += v; }
  }
  __syncthreads();
  if (i < n) rowptr[i] = s[t];
}
// atomic-free fill: position = rowptr[dst] + slot (slot from the hist atomic)
__global__ void k_fill(const int* __restrict__ src, const int* __restrict__ dst,
                       const float* __restrict__ w, const int* __restrict__ rowptr,
                       const int* __restrict__ slot, uint2* __restrict__ edges, int E) {
  int e = blockIdx.x * 256 + threadIdx.x;
  if (e < E) {
    int d = dst[e];
    uint2 ev;
    ev.x = (u32)src[e];
    ev.y = __float_as_uint(w[e]);
    edges[rowptr[d] + slot[e]] = ev;
  }
}

// one wave per row: bitonic-sort edges[p..p+c) ascending by (col,w_bits),
// then dinv[row] = rsqrt(1 + sum(w)) in a fixed reduction order. Deterministic.
__global__ __launch_bounds__(256) void k_sortrow(
    uint2* __restrict__ edges, const int* __restrict__ rowptr,
    const int* __restrict__ cnt, float* __restrict__ dinv, int n) {
  int wave = threadIdx.x >> 6, lane = threadIdx.x & 63;
  int row = blockIdx.x * 4 + wave;
  if (row >= n) return;
  int p = rowptr[row], c = cnt[row];
  if (c <= 64) {
    u32 kc = 0xFFFFFFFFu, kw = 0xFFFFFFFFu;
    if (lane < c) { uint2 e = edges[p + lane]; kc = e.x; kw = e.y; }
#pragma unroll
    for (int k = 2; k <= 64; k <<= 1) {
#pragma unroll
      for (int j = k >> 1; j > 0; j >>= 1) {
        u32 oc = __shfl_xor(kc, j, 64);
        u32 ow = __shfl_xor(kw, j, 64);
        bool up = ((lane & k) == 0);
        bool lower = ((lane & j) == 0);
        bool gt = (kc > oc) || (kc == oc && kw > ow);
        bool lt = (kc < oc) || (kc == oc && kw < ow);
        bool swap = up ? (lower ? gt : lt) : (lower ? lt : gt);
        if (swap) { kc = oc; kw = ow; }
      }
    }
    float s = (lane < c) ? __uint_as_float(kw) : 0.f;
#pragma unroll
    for (int off = 1; off < 64; off <<= 1) s += __shfl_xor(s, off, 64);
    if (lane < c) { uint2 e; e.x = kc; e.y = kw; edges[p + lane] = e; }
    if (lane == 0) dinv[row] = rsqrtf(1.0f + s);
  } else {
    if (lane == 0) {  // rare fallback, deterministic serial insertion sort
      for (int i = 1; i < c; i++) {
        uint2 key = edges[p + i];
        int j2 = i - 1;
        while (j2 >= 0) {
          uint2 a = edges[p + j2];
          bool gt = (a.x > key.x) || (a.x == key.x && a.y > key.y);
          if (!gt) break;
          edges[p + j2 + 1] = a; j2--;
        }
        edges[p + j2 + 1] = key;
      }
      float s = 0.f;
      for (int i = 0; i < c; i++) s += __uint_as_float(edges[p + i].y);
      dinv[row] = rsqrtf(1.0f + s);
    }
  }
}

// replace w with norm = dinv[col]*w*dinv[row], in sorted order (deterministic).
// Separate streaming pass (edges L2/L3-hot after sortrow): r12 showed doing
// this inside the agg gather loop costs +15us vs +8us here.
__global__ __launch_bounds__(256) void k_val(
    uint2* __restrict__ edges, const int* __restrict__ rowptr,
    const int* __restrict__ cnt, const float* __restrict__ dinv, int n) {
  int wave = threadIdx.x >> 6, lane = threadIdx.x & 63;
  int row = blockIdx.x * 4 + wave;
  if (row >= n) return;
  int p = rowptr[row], c = cnt[row];
  float dr = dinv[row];
  for (int l = lane; l < c; l += 64) {
    uint2 e = edges[p + l];
    float w = __uint_as_float(e.y);
    e.y = __float_as_uint(dinv[(int)e.x] * w * dr);
    edges[p + l] = e;
  }
}

// ---------- aggregation (r9 structure; gather loop minimal; at fetch floor) ----------
template <int D, int OUTF32, int RELU, int HASB, int U>
__global__ __launch_bounds__(128) void k_agg(
    const u16* __restrict__ H, const int* __restrict__ rowptr,
    const int* __restrict__ cnt, const uint2* __restrict__ edges,
    const float* __restrict__ dinv,
    const float* __restrict__ bias, void* __restrict__ outv) {
  constexpr int RL = D / 8;     // lanes per row at 16B/lane
  constexpr int EPW = 64 / RL;  // edges in flight per slot
  int wave = threadIdx.x >> 6, lane = threadIdx.x & 63;
  int node = blockIdx.x * 2 + wave;
  if (node >= NN) return;
  const int sub = lane / RL;
  const int rl = lane & (RL - 1);
  const int base = rl * 8;
  float acc[8] = {};
  if (sub == 0) {
    float dv = dinv[node];
    float sw = dv * dv;
    uint4 q = *(const uint4*)(H + (size_t)node * D + base);
    float f[8]; unpack8(q, f);
#pragma unroll
    for (int j = 0; j < 8; j++) acc[j] = sw * f[j];
  }
  const int p = rowptr[node], c = cnt[node];
  for (int e0 = 0; e0 < c; e0 += EPW * U) {
    uint4 q[U];
    float v[U];
#pragma unroll
    for (int u = 0; u < U; u++) {
      int id = e0 + sub + u * EPW;
      bool ok = id < c;
      uint2 ev = edges[p + (ok ? id : 0)];
      v[u] = ok ? __uint_as_float(ev.y) : 0.f;
      int cs = ok ? (int)ev.x : node;  // dead slots re-read own (L1-hot) row
      q[u] = *(const uint4*)(H + (size_t)cs * D + base);
    }
#pragma unroll
    for (int u = 0; u < U; u++) {
      float f[8]; unpack8(q[u], f);
#pragma unroll
      for (int j = 0; j < 8; j++) acc[j] += v[u] * f[j];
    }
  }
#pragma unroll
  for (int j = 0; j < 8; j++) {
#pragma unroll
    for (int off = RL; off < 64; off <<= 1)
      acc[j] += __shfl_xor(acc[j], off, 64);
  }
  if (sub == 0) {
#pragma unroll
    for (int j = 0; j < 8; j++) {
      float v2 = acc[j];
      if (HASB) v2 += bias[base + j];
      if (RELU) v2 = fmaxf(v2, 0.f);
      acc[j] = v2;
    }
    if (OUTF32) {
      float* o = (float*)outv + (size_t)node * D + base;
      float4 f0 = {acc[0], acc[1], acc[2], acc[3]};
      float4 f1 = {acc[4], acc[5], acc[6], acc[7]};
      *(float4*)o = f0;
      *(float4*)(o + 4) = f1;
    } else {
      u16* o = (u16*)outv + (size_t)node * D + base;
      uint4 u;
      u.x = (u32)f2bf(acc[0]) | ((u32)f2bf(acc[1]) << 16);
      u.y = (u32)f2bf(acc[2]) | ((u32)f2bf(acc[3]) << 16);
      u.z = (u32)f2bf(acc[4]) | ((u32)f2bf(acc[5]) << 16);
      u.w = (u32)f2bf(acc[6]) | ((u32)f2bf(acc[7]) << 16);
      *(uint4*)o = u;
    }
  }
}

// ---------- bf16 MFMA GEMM, 256x128 tile, 8 waves, XCD-swizzled 1D grid ----------
template <int RELU, int HASB, int NYB>
__global__ __launch_bounds__(512) void k_gemm(
    const u16* __restrict__ A, const u16* __restrict__ Bt,
    const float* __restrict__ bias, u16* __restrict__ C, int M, int Nd, int K) {
  __shared__ u16 As[256 * 64];
  __shared__ u16 Bs[128 * 64];
  const int tid = threadIdx.x;
  const int wave = tid >> 6, lane = tid & 63;
  const int nwg = gridDim.x;
  const int orig = blockIdx.x;
  const int xcd = orig & 7;
  const int q = nwg >> 3, r = nwg & 7;
  const int wgid = (xcd < r ? xcd * (q + 1) : r * (q + 1) + (xcd - r) * q) + (orig >> 3);
  const int m0 = (wgid / NYB) * 256, n0 = (wgid % NYB) * 128;
  const int wr = wave >> 1, wc = wave & 1;  // 4x2 waves, each 64x64 out
  f32x4 acc[4][4] = {};

  for (int k0 = 0; k0 < K; k0 += 64) {
#pragma unroll
    for (int i = 0; i < 4; i++) {
      int rr = i * 64 + wave * 8 + (lane >> 3);
      int rg = m0 + rr; rg = rg < M ? rg : M - 1;  // clamp tail (masked in epilogue)
      const u16* ga = A + (size_t)rg * K + k0 + (lane & 7) * 8;
      __builtin_amdgcn_global_load_lds(
          (const __attribute__((address_space(1))) void*)ga,
          (__attribute__((address_space(3))) void*)&As[(i * 64 + wave * 8) * 64], 16, 0, 0);
    }
#pragma unroll
    for (int i = 0; i < 2; i++) {
      int rr = i * 64 + wave * 8 + (lane >> 3);
      int ng = n0 + rr;  // Nd % 128 == 0
      const u16* gb = Bt + (size_t)ng * K + k0 + (lane & 7) * 8;
      __builtin_amdgcn_global_load_lds(
          (const __attribute__((address_space(1))) void*)gb,
          (__attribute__((address_space(3))) void*)&Bs[(i * 64 + wave * 8) * 64], 16, 0, 0);
    }
    __syncthreads();
#pragma unroll
    for (int kk = 0; kk < 2; kk++) {
      bf16x8 af[4], bfr[4];
#pragma unroll
      for (int mi = 0; mi < 4; mi++)
        af[mi] = *(const bf16x8*)&As[(wr * 64 + mi * 16 + (lane & 15)) * 64 + kk * 32 + (lane >> 4) * 8];
#pragma unroll
      for (int ni = 0; ni < 4; ni++)
        bfr[ni] = *(const bf16x8*)&Bs[(wc * 64 + ni * 16 + (lane & 15)) * 64 + kk * 32 + (lane >> 4) * 8];
#pragma unroll
      for (int mi = 0; mi < 4; mi++)
#pragma unroll
        for (int ni = 0; ni < 4; ni++)
          acc[mi][ni] = __builtin_amdgcn_mfma_f32_16x16x32_bf16(af[mi], bfr[ni], acc[mi][ni], 0, 0, 0);
    }
    __syncthreads();
  }
  const int nb = n0 + wc * 64 + (lane & 15);
  float bv[4];
#pragma unroll
  for (int ni = 0; ni < 4; ni++) bv[ni] = HASB ? bias[nb + ni * 16] : 0.f;
#pragma unroll
  for (int mi = 0; mi < 4; mi++) {
#pragma unroll
    for (int rr = 0; rr < 4; rr++) {
      int row = m0 + wr * 64 + mi * 16 + (lane >> 4) * 4 + rr;
      if (row < M) {
#pragma unroll
        for (int ni = 0; ni < 4; ni++) {
          float v = acc[mi][ni][rr] + bv[ni];
          if (RELU) v = fmaxf(v, 0.f);
          C[(size_t)row * Nd + nb + ni * 16] = f2bf(v);
        }
      }
    }
  }
}

extern "C" void kernel_launch(void* const* d_in, const int* in_sizes, int n_in,
                              void* d_out, int out_size, void* d_ws, size_t ws_size,
                              hipStream_t stream) {
  const float* x  = (const float*)d_in[0];
  const int*   ei = (const int*)d_in[1];   // [2][NE]: src then dst
  const float* ea = (const float*)d_in[2];
  const float* W1 = (const float*)d_in[3];
  const float* b1 = (const float*)d_in[4];
  const float* W2 = (const float*)d_in[5];
  const float* b2 = (const float*)d_in[6];
  const float* W3 = (const float*)d_in[7];
  const float* b3 = (const float*)d_in[8];
  const int* e_src = ei;
  const int* e_dst = ei + NE;

  size_t off = 0;
  auto carve = [&](size_t bytes) -> void* {
    void* r = (char*)d_ws + off;
    off += (bytes + 255) & ~(size_t)255;
    return r;
  };
  int*   counts = (int*)carve(NN * 4);
  float* dinv   = (float*)carve(NN * 4);
  int*   rowptr = (int*)carve(NN * 4);
  int*   bsum   = (int*)carve(256 * 4);
  int*   slot   = (int*)carve((size_t)NE * 4);
  uint2* edges  = (uint2*)carve((size_t)NE * 8);
  u16*   Wt1    = (u16*)carve(512 * 256 * 2);
  u16*   Wt2    = (u16*)carve(256 * 512 * 2);
  u16*   Wt3    = (u16*)carve(128 * 256 * 2);
  u16*   R0     = (u16*)carve((size_t)NN * 256 * 2);  // x_bf -> t2 -> t3
  u16*   R1     = (u16*)carve((size_t)NN * 256 * 2);  // agg1 -> h2
  u16*   R2     = (u16*)carve((size_t)NN * 512 * 2);  // h1

  const int NB_N = (NN + 255) / 256;   // 196
  const int NB_E = (NE + 255) / 256;   // 3125
  const int ROW_B = (NN + 3) / 4;      // sortrow/val: 4 rows per 256-thr block
  const int AGG_B = (NN + 1) / 2;      // agg: 2 rows per 128-thr block

  hipMemsetAsync(counts, 0, (size_t)NN * 4, stream);

  // hist(+slot) interleaved with casts
  k_hist_cast<<<T_B, 256, 0, stream>>>(
      e_dst, counts, slot, x, W1, W2, W3, R0, Wt1, Wt2, Wt3);
  k_scan_part<<<NB_N, 256, 0, stream>>>(counts, bsum, NN);
  k_scan_fin<<<NB_N, 256, 0, stream>>>(counts, bsum, rowptr, NN);
  k_fill<<<NB_E, 256, 0, stream>>>(e_src, e_dst, ea, rowptr, slot, edges, NE);
  k_sortrow<<<ROW_B, 256, 0, stream>>>(edges, rowptr, counts, dinv, NN);
  k_val<<<ROW_B, 256, 0, stream>>>(edges, rowptr, counts, dinv, NN);

  // L1: agg1 = A*x ; h1 = relu(agg1*W1 + b1)
  k_agg<256, 0, 0, 0, 4><<<AGG_B, 128, 0, stream>>>(R0, rowptr, counts, edges, dinv, nullptr, R1);
  k_gemm<1, 1, 4><<<196 * 4, 512, 0, stream>>>(R1, Wt1, b1, R2, NN, 512, 256);
  // L2: t2 = h1*W2 ; h2 = relu(A*t2 + b2)
  k_gemm<0, 0, 2><<<196 * 2, 512, 0, stream>>>(R2, Wt2, nullptr, R0, NN, 256, 512);
  k_agg<256, 0, 1, 1, 4><<<AGG_B, 128, 0, stream>>>(R0, rowptr, counts, edges, dinv, b2, R1);
  // L3: t3 = h2*W3 ; out = A*t3 + b3
  k_gemm<0, 0, 1><<<196 * 1, 512, 0, stream>>>(R1, Wt3, nullptr, R0, NN, 128, 256);
  k_agg<128, 1, 0, 1, 4><<<AGG_B, 128, 0, stream>>>(R0, rowptr, counts, edges, dinv, b3, d_out);
}

// Round 14
// 337.295 us; speedup vs baseline: 1.0139x; 1.0139x over previous
//
#include <hip/hip_runtime.h>
#include <cstdint>
#include <cstddef>

typedef unsigned short u16;
typedef unsigned int u32;
typedef unsigned long long u64;

#define NN 50000
#define NE 800000

typedef __attribute__((ext_vector_type(8))) short bf16x8;
typedef __attribute__((ext_vector_type(4))) float f32x4;

__device__ __forceinline__ u16 f2bf(float f) {
  union { float f; u32 i; } v; v.f = f;
  return (u16)((v.i + 0x7FFFu + ((v.i >> 16) & 1u)) >> 16);
}
__device__ __forceinline__ void bf2x2(u32 w, float& a, float& b) {
  union { u32 i; float f; } lo, hi;
  lo.i = w << 16; hi.i = w & 0xFFFF0000u;
  a = lo.f; b = hi.f;
}
__device__ __forceinline__ void unpack8(const uint4& q, float* f) {
  bf2x2(q.x, f[0], f[1]); bf2x2(q.y, f[2], f[3]);
  bf2x2(q.z, f[4], f[5]); bf2x2(q.w, f[6], f[7]);
}

#define XGROUPS (NN * 256 / 4)   // 3.2M float4 groups of x
#define NA_B 782                 // ceil(NE/1024) atomic blocks (ILP-4)
// cast blocks needed: (XGROUPS+294912)/256 = 13652 exactly.
// T_B=14455: #atomic(b%18==17) = 803 (last is no-op), #cast = 13652. ci is a
// bijection onto [0,13652): b=18m+r (r<17) -> ci=17m+r; b=14454 -> ci=13651.
#define T_B 14455
#define WSCALE 33554432.0f       // 2^25 fixed-point weight scale
#define WMASK  0xFFFFFFFFFFull   // low 40 bits

// ---------- fused: packed count|wsum histogram (ILP-4) interleaved 1:17 with casts ----------
// One u64 atomic per edge: high 24 bits = count (returned old -> slot),
// low 40 bits = sum of round(w*2^25) (integer sum -> order-independent,
// deterministic). deg and dinv become available at scan time, so k_fill can
// write final norms and the k_val pass (r13: ~15-20us scattered-gather) dies.
__global__ void k_hist_cast(const int* __restrict__ dst, const float* __restrict__ w,
                            u64* __restrict__ degpack, int* __restrict__ slot,
                            const float* __restrict__ x, const float* __restrict__ W1,
                            const float* __restrict__ W2, const float* __restrict__ W3,
                            u16* __restrict__ xb, u16* __restrict__ Wt1,
                            u16* __restrict__ Wt2, u16* __restrict__ Wt3) {
  int b = blockIdx.x;
  int q = b / 18, r = b - q * 18;
  if (r == 17) {
    if (q >= NA_B) return;
    int ebase = q * 1024 + threadIdx.x;
    int ds[4]; u64 inc[4]; bool ok[4];
#pragma unroll
    for (int u = 0; u < 4; u++) {
      int e = ebase + u * 256;
      ok[u] = e < NE;
      ds[u] = ok[u] ? dst[e] : 0;
      u32 wfix = ok[u] ? (u32)(w[e] * WSCALE + 0.5f) : 0u;
      inc[u] = (1ULL << 40) | (u64)wfix;
    }
    int sl[4];
#pragma unroll
    for (int u = 0; u < 4; u++)
      if (ok[u]) sl[u] = (int)(atomicAdd(&degpack[ds[u]], inc[u]) >> 40);
#pragma unroll
    for (int u = 0; u < 4; u++)
      if (ok[u]) slot[ebase + u * 256] = sl[u];
  } else {
    int ci = b - q;  // cast-block index (atomic blocks before b = q)
    int i = ci * 256 + threadIdx.x;
    if (i < XGROUPS) {
      float4 f = ((const float4*)x)[i];
      uint2 u;
      u.x = (u32)f2bf(f.x) | ((u32)f2bf(f.y) << 16);
      u.y = (u32)f2bf(f.z) | ((u32)f2bf(f.w) << 16);
      ((uint2*)xb)[i] = u;
    } else {
      int j = i - XGROUPS;
      if (j < 131072) {                    // W1: [256][512] -> Wt1[512][256]
        int k = j >> 9, n = j & 511;
        Wt1[n * 256 + k] = f2bf(W1[j]);
      } else if (j < 262144) {             // W2: [512][256] -> Wt2[256][512]
        int j2 = j - 131072;
        int k = j2 >> 8, n = j2 & 255;
        Wt2[n * 512 + k] = f2bf(W2[j2]);
      } else if (j < 294912) {             // W3: [256][128] -> Wt3[128][256]
        int j2 = j - 262144;
        int k = j2 >> 7, n = j2 & 127;
        Wt3[n * 256 + k] = f2bf(W3[j2]);
      }
    }
  }
}

__global__ void k_scan_part(const u64* __restrict__ degpack, int* __restrict__ bsum, int n) {
  __shared__ int s[256];
  int i = blockIdx.x * 256 + threadIdx.x;
  s[threadIdx.x] = (i < n) ? (int)(degpack[i] >> 40) : 0;
  __syncthreads();
  for (int o = 128; o > 0; o >>= 1) {
    if (threadIdx.x < o) s[threadIdx.x] += s[threadIdx.x + o];
    __syncthreads();
  }
  if (threadIdx.x == 0) bsum[blockIdx.x] = s[0];
}
// scan_fin: rowptr + counts + dinv, all from degpack (inter-block prefix in-block)
__global__ void k_scan_fin(const u64* __restrict__ degpack, const int* __restrict__ bsum,
                           int* __restrict__ rowptr, int* __restrict__ counts,
                           float* __restrict__ dinv, int n) {
  __shared__ int s[256];
  __shared__ int pre[256];
  int t = threadIdx.x;
  int i = blockIdx.x * 256 + t;
  u64 dp = (i < n) ? degpack[i] : 0ull;
  int c = (int)(dp >> 40);
  pre[t] = (t < blockIdx.x) ? bsum[t] : 0;  // nb <= 256
  s[t] = c;
  __syncthreads();
  for (int o = 128; o > 0; o >>= 1) {
    if (t < o) pre[t] += pre[t + o];
    __syncthreads();
  }
  if (t == 0) {
    int run = pre[0];
    for (int j = 0; j < 256; j++) { int v = s[j]; s[j] = run; run += v; }
  }
  __syncthreads();
  if (i < n) {
    rowptr[i] = s[t];
    counts[i] = c;
    float wsum = (float)(dp & WMASK) * (1.0f / WSCALE);
    dinv[i] = rsqrtf(1.0f + wsum);
  }
}
// atomic-free fill writing FINAL norms: pos = rowptr[dst]+slot; value is a
// pure function of the edge (deterministic); dinv reads are L2-hot (200 KB).
__global__ void k_fill(const int* __restrict__ src, const int* __restrict__ dst,
                       const float* __restrict__ w, const int* __restrict__ rowptr,
                       const int* __restrict__ slot, const float* __restrict__ dinv,
                       uint2* __restrict__ edges, int E) {
  int e = blockIdx.x * 256 + threadIdx.x;
  if (e < E) {
    int d = dst[e], s0 = src[e];
    uint2 ev;
    ev.x = (u32)s0;
    ev.y = __float_as_uint(dinv[s0] * w[e] * dinv[d]);  // (dinv[col]*w)*dinv[row]
    edges[rowptr[d] + slot[e]] = ev;
  }
}

// one wave per row: bitonic-sort edges[p..p+c) ascending by (col,norm_bits).
// Canonicalizes atomic placement order -> deterministic agg sums.
__global__ __launch_bounds__(256) void k_sortrow(
    uint2* __restrict__ edges, const int* __restrict__ rowptr,
    const int* __restrict__ cnt, int n) {
  int wave = threadIdx.x >> 6, lane = threadIdx.x & 63;
  int row = blockIdx.x * 4 + wave;
  if (row >= n) return;
  int p = rowptr[row], c = cnt[row];
  if (c <= 64) {
    u32 kc = 0xFFFFFFFFu, kw = 0xFFFFFFFFu;
    if (lane < c) { uint2 e = edges[p + lane]; kc = e.x; kw = e.y; }
#pragma unroll
    for (int k = 2; k <= 64; k <<= 1) {
#pragma unroll
      for (int j = k >> 1; j > 0; j >>= 1) {
        u32 oc = __shfl_xor(kc, j, 64);
        u32 ow = __shfl_xor(kw, j, 64);
        bool up = ((lane & k) == 0);
        bool lower = ((lane & j) == 0);
        bool gt = (kc > oc) || (kc == oc && kw > ow);
        bool lt = (kc < oc) || (kc == oc && kw < ow);
        bool swap = up ? (lower ? gt : lt) : (lower ? lt : gt);
        if (swap) { kc = oc; kw = ow; }
      }
    }
    if (lane < c) { uint2 e; e.x = kc; e.y = kw; edges[p + lane] = e; }
  } else {
    if (lane == 0) {  // rare fallback, deterministic serial insertion sort
      for (int i = 1; i < c; i++) {
        uint2 key = edges[p + i];
        int j2 = i - 1;
        while (j2 >= 0) {
          uint2 a = edges[p + j2];
          bool gt = (a.x > key.x) || (a.x == key.x && a.y > key.y);
          if (!gt) break;
          edges[p + j2 + 1] = a; j2--;
        }
        edges[p + j2 + 1] = key;
      }
    }
  }
}

// ---------- aggregation (r9 structure; gather loop minimal; at fetch floor) ----------
template <int D, int OUTF32, int RELU, int HASB, int U>
__global__ __launch_bounds__(128) void k_agg(
    const u16* __restrict__ H, const int* __restrict__ rowptr,
    const int* __restrict__ cnt, const uint2* __restrict__ edges,
    const float* __restrict__ dinv,
    const float* __restrict__ bias, void* __restrict__ outv) {
  constexpr int RL = D / 8;     // lanes per row at 16B/lane
  constexpr int EPW = 64 / RL;  // edges in flight per slot
  int wave = threadIdx.x >> 6, lane = threadIdx.x & 63;
  int node = blockIdx.x * 2 + wave;
  if (node >= NN) return;
  const int sub = lane / RL;
  const int rl = lane & (RL - 1);
  const int base = rl * 8;
  float acc[8] = {};
  if (sub == 0) {
    float dv = dinv[node];
    float sw = dv * dv;
    uint4 q = *(const uint4*)(H + (size_t)node * D + base);
    float f[8]; unpack8(q, f);
#pragma unroll
    for (int j = 0; j < 8; j++) acc[j] = sw * f[j];
  }
  const int p = rowptr[node], c = cnt[node];
  for (int e0 = 0; e0 < c; e0 += EPW * U) {
    uint4 q[U];
    float v[U];
#pragma unroll
    for (int u = 0; u < U; u++) {
      int id = e0 + sub + u * EPW;
      bool ok = id < c;
      uint2 ev = edges[p + (ok ? id : 0)];
      v[u] = ok ? __uint_as_float(ev.y) : 0.f;
      int cs = ok ? (int)ev.x : node;  // dead slots re-read own (L1-hot) row
      q[u] = *(const uint4*)(H + (size_t)cs * D + base);
    }
#pragma unroll
    for (int u = 0; u < U; u++) {
      float f[8]; unpack8(q[u], f);
#pragma unroll
      for (int j = 0; j < 8; j++) acc[j] += v[u] * f[j];
    }
  }
#pragma unroll
  for (int j = 0; j < 8; j++) {
#pragma unroll
    for (int off = RL; off < 64; off <<= 1)
      acc[j] += __shfl_xor(acc[j], off, 64);
  }
  if (sub == 0) {
#pragma unroll
    for (int j = 0; j < 8; j++) {
      float v2 = acc[j];
      if (HASB) v2 += bias[base + j];
      if (RELU) v2 = fmaxf(v2, 0.f);
      acc[j] = v2;
    }
    if (OUTF32) {
      float* o = (float*)outv + (size_t)node * D + base;
      float4 f0 = {acc[0], acc[1], acc[2], acc[3]};
      float4 f1 = {acc[4], acc[5], acc[6], acc[7]};
      *(float4*)o = f0;
      *(float4*)(o + 4) = f1;
    } else {
      u16* o = (u16*)outv + (size_t)node * D + base;
      uint4 u;
      u.x = (u32)f2bf(acc[0]) | ((u32)f2bf(acc[1]) << 16);
      u.y = (u32)f2bf(acc[2]) | ((u32)f2bf(acc[3]) << 16);
      u.z = (u32)f2bf(acc[4]) | ((u32)f2bf(acc[5]) << 16);
      u.w = (u32)f2bf(acc[6]) | ((u32)f2bf(acc[7]) << 16);
      *(uint4*)o = u;
    }
  }
}

// ---------- bf16 MFMA GEMM, 256x128 tile, 8 waves, XCD-swizzled 1D grid ----------
template <int RELU, int HASB, int NYB>
__global__ __launch_bounds__(512) void k_gemm(
    const u16* __restrict__ A, const u16* __restrict__ Bt,
    const float* __restrict__ bias, u16* __restrict__ C, int M, int Nd, int K) {
  __shared__ u16 As[256 * 64];
  __shared__ u16 Bs[128 * 64];
  const int tid = threadIdx.x;
  const int wave = tid >> 6, lane = tid & 63;
  const int nwg = gridDim.x;
  const int orig = blockIdx.x;
  const int xcd = orig & 7;
  const int q = nwg >> 3, r = nwg & 7;
  const int wgid = (xcd < r ? xcd * (q + 1) : r * (q + 1) + (xcd - r) * q) + (orig >> 3);
  const int m0 = (wgid / NYB) * 256, n0 = (wgid % NYB) * 128;
  const int wr = wave >> 1, wc = wave & 1;  // 4x2 waves, each 64x64 out
  f32x4 acc[4][4] = {};

  for (int k0 = 0; k0 < K; k0 += 64) {
#pragma unroll
    for (int i = 0; i < 4; i++) {
      int rr = i * 64 + wave * 8 + (lane >> 3);
      int rg = m0 + rr; rg = rg < M ? rg : M - 1;  // clamp tail (masked in epilogue)
      const u16* ga = A + (size_t)rg * K + k0 + (lane & 7) * 8;
      __builtin_amdgcn_global_load_lds(
          (const __attribute__((address_space(1))) void*)ga,
          (__attribute__((address_space(3))) void*)&As[(i * 64 + wave * 8) * 64], 16, 0, 0);
    }
#pragma unroll
    for (int i = 0; i < 2; i++) {
      int rr = i * 64 + wave * 8 + (lane >> 3);
      int ng = n0 + rr;  // Nd % 128 == 0
      const u16* gb = Bt + (size_t)ng * K + k0 + (lane & 7) * 8;
      __builtin_amdgcn_global_load_lds(
          (const __attribute__((address_space(1))) void*)gb,
          (__attribute__((address_space(3))) void*)&Bs[(i * 64 + wave * 8) * 64], 16, 0, 0);
    }
    __syncthreads();
#pragma unroll
    for (int kk = 0; kk < 2; kk++) {
      bf16x8 af[4], bfr[4];
#pragma unroll
      for (int mi = 0; mi < 4; mi++)
        af[mi] = *(const bf16x8*)&As[(wr * 64 + mi * 16 + (lane & 15)) * 64 + kk * 32 + (lane >> 4) * 8];
#pragma unroll
      for (int ni = 0; ni < 4; ni++)
        bfr[ni] = *(const bf16x8*)&Bs[(wc * 64 + ni * 16 + (lane & 15)) * 64 + kk * 32 + (lane >> 4) * 8];
#pragma unroll
      for (int mi = 0; mi < 4; mi++)
#pragma unroll
        for (int ni = 0; ni < 4; ni++)
          acc[mi][ni] = __builtin_amdgcn_mfma_f32_16x16x32_bf16(af[mi], bfr[ni], acc[mi][ni], 0, 0, 0);
    }
    __syncthreads();
  }
  const int nb = n0 + wc * 64 + (lane & 15);
  float bv[4];
#pragma unroll
  for (int ni = 0; ni < 4; ni++) bv[ni] = HASB ? bias[nb + ni * 16] : 0.f;
#pragma unroll
  for (int mi = 0; mi < 4; mi++) {
#pragma unroll
    for (int rr = 0; rr < 4; rr++) {
      int row = m0 + wr * 64 + mi * 16 + (lane >> 4) * 4 + rr;
      if (row < M) {
#pragma unroll
        for (int ni = 0; ni < 4; ni++) {
          float v = acc[mi][ni][rr] + bv[ni];
          if (RELU) v = fmaxf(v, 0.f);
          C[(size_t)row * Nd + nb + ni * 16] = f2bf(v);
        }
      }
    }
  }
}

extern "C" void kernel_launch(void* const* d_in, const int* in_sizes, int n_in,
                              void* d_out, int out_size, void* d_ws, size_t ws_size,
                              hipStream_t stream) {
  const float* x  = (const float*)d_in[0];
  const int*   ei = (const int*)d_in[1];   // [2][NE]: src then dst
  const float* ea = (const float*)d_in[2];
  const float* W1 = (const float*)d_in[3];
  const float* b1 = (const float*)d_in[4];
  const float* W2 = (const float*)d_in[5];
  const float* b2 = (const float*)d_in[6];
  const float* W3 = (const float*)d_in[7];
  const float* b3 = (const float*)d_in[8];
  const int* e_src = ei;
  const int* e_dst = ei + NE;

  size_t off = 0;
  auto carve = [&](size_t bytes) -> void* {
    void* r = (char*)d_ws + off;
    off += (bytes + 255) & ~(size_t)255;
    return r;
  };
  u64*   degpack = (u64*)carve(NN * 8);
  int*   counts  = (int*)carve(NN * 4);
  float* dinv    = (float*)carve(NN * 4);
  int*   rowptr  = (int*)carve(NN * 4);
  int*   bsum    = (int*)carve(256 * 4);
  int*   slot    = (int*)carve((size_t)NE * 4);
  uint2* edges   = (uint2*)carve((size_t)NE * 8);
  u16*   Wt1     = (u16*)carve(512 * 256 * 2);
  u16*   Wt2     = (u16*)carve(256 * 512 * 2);
  u16*   Wt3     = (u16*)carve(128 * 256 * 2);
  u16*   R0      = (u16*)carve((size_t)NN * 256 * 2);  // x_bf -> t2 -> t3
  u16*   R1      = (u16*)carve((size_t)NN * 256 * 2);  // agg1 -> h2
  u16*   R2      = (u16*)carve((size_t)NN * 512 * 2);  // h1

  const int NB_N = (NN + 255) / 256;   // 196
  const int NB_E = (NE + 255) / 256;   // 3125
  const int ROW_B = (NN + 3) / 4;      // sortrow: 4 rows per 256-thr block
  const int AGG_B = (NN + 1) / 2;      // agg: 2 rows per 128-thr block

  hipMemsetAsync(degpack, 0, (size_t)NN * 8, stream);

  // packed hist (count|wsum) interleaved with casts
  k_hist_cast<<<T_B, 256, 0, stream>>>(
      e_dst, ea, degpack, slot, x, W1, W2, W3, R0, Wt1, Wt2, Wt3);
  k_scan_part<<<NB_N, 256, 0, stream>>>(degpack, bsum, NN);
  k_scan_fin<<<NB_N, 256, 0, stream>>>(degpack, bsum, rowptr, counts, dinv, NN);
  k_fill<<<NB_E, 256, 0, stream>>>(e_src, e_dst, ea, rowptr, slot, dinv, edges, NE);
  k_sortrow<<<ROW_B, 256, 0, stream>>>(edges, rowptr, counts, NN);

  // L1: agg1 = A*x ; h1 = relu(agg1*W1 + b1)
  k_agg<256, 0, 0, 0, 4><<<AGG_B, 128, 0, stream>>>(R0, rowptr, counts, edges, dinv, nullptr, R1);
  k_gemm<1, 1, 4><<<196 * 4, 512, 0, stream>>>(R1, Wt1, b1, R2, NN, 512, 256);
  // L2: t2 = h1*W2 ; h2 = relu(A*t2 + b2)
  k_gemm<0, 0, 2><<<196 * 2, 512, 0, stream>>>(R2, Wt2, nullptr, R0, NN, 256, 512);
  k_agg<256, 0, 1, 1, 4><<<AGG_B, 128, 0, stream>>>(R0, rowptr, counts, edges, dinv, b2, R1);
  // L3: t3 = h2*W3 ; out = A*t3 + b3
  k_gemm<0, 0, 1><<<196 * 1, 512, 0, stream>>>(R1, Wt3, nullptr, R0, NN, 128, 256);
  k_agg<128, 1, 0, 1, 4><<<AGG_B, 128, 0, stream>>>(R0, rowptr, counts, edges, dinv, b3, d_out);
}